// Round 1
// 3638.338 us; speedup vs baseline: 1.0669x; 1.0669x over previous
//
#include <hip/hip_runtime.h>
#include <hip/hip_bf16.h>
#include <stdint.h>

// Linear4Bit: x f32 [8,2048,4096], wq int32 [12288,2048] (1 byte/word),
// norm f32 [12288,1], bias f32 [12288], out f32 [16384,12288].
// y = x @ dequant(W)^T + bias : M=16384, N=12288, K=4096.
//
// R1: 256x256 tile double-buffered 2-phase GEMM. Theory: 128^2 tiles staged
// 24 GiB of A/B re-reads while the 768 MiB C stream thrashed L3 -> staging
// ran at HBM rate (~6.8 TB/s) -> 430 TF. 256^2 halves staged bytes; dbuf
// hides load latency under MFMA (1 block/CU -> no cross-block overlap);
// XCD-banded swizzle makes the per-XCD A panel L2-resident; nontemporal C
// stores stop L3 pollution.
#define M_TOT 16384
#define N_TOT 12288
#define K_TOT 4096
#define BM 256
#define BN 256
#define BK 64

typedef __bf16 bf16;
typedef __bf16 bf16x8 __attribute__((ext_vector_type(8)));
typedef float f32x4 __attribute__((ext_vector_type(4)));

typedef __attribute__((address_space(1))) const void gvoid;
typedef __attribute__((address_space(3))) void lvoid;

__device__ __forceinline__ void async_copy16(const void* g, void* l) {
    // global -> LDS direct DMA, 16B/lane; LDS dst = wave-uniform base + lane*16.
    __builtin_amdgcn_global_load_lds((gvoid*)g, (lvoid*)l, 16, 0, 0);
}

// ---------------------------------------------------------------------------
// x: f32 -> bf16 into workspace. 8 elems / thread (32B read, 16B write).
// ---------------------------------------------------------------------------
__global__ __launch_bounds__(256) void convert_x_kernel(
        const float* __restrict__ x, bf16* __restrict__ xb) {
    size_t t = (size_t)blockIdx.x * 256 + threadIdx.x;   // 8,388,608 threads
    const float4* xv = (const float4*)x;
    float4 a = xv[2 * t], b = xv[2 * t + 1];
    bf16x8 o = { (bf16)a.x, (bf16)a.y, (bf16)a.z, (bf16)a.w,
                 (bf16)b.x, (bf16)b.y, (bf16)b.z, (bf16)b.w };
    ((bf16x8*)xb)[t] = o;
}

// ---------------------------------------------------------------------------
// dequant packed nibbles -> bf16 W[N,K] into workspace. 4 words -> 8 bf16.
// low nibble = even position, high nibble = odd. w = q/15 * 2n - n.
// ---------------------------------------------------------------------------
__global__ __launch_bounds__(256) void dequant_kernel(
        const int* __restrict__ wq, const float* __restrict__ norm,
        bf16* __restrict__ wout) {
    int t = blockIdx.x * 256 + threadIdx.x;   // 6,291,456 threads
    int4 qw = ((const int4*)wq)[t];
    int row = t >> 9;                          // 512 threads per 2048-word row
    float n = norm[row];
    float s = n * (2.0f / 15.0f);
    int v[4] = {qw.x, qw.y, qw.z, qw.w};
    bf16x8 o;
#pragma unroll
    for (int u = 0; u < 4; ++u) {
        o[2*u]   = (bf16)((float)(v[u] & 15)        * s - n);
        o[2*u+1] = (bf16)((float)((v[u] >> 4) & 15) * s - n);
    }
    ((bf16x8*)wout)[t] = o;
}

// ---------------------------------------------------------------------------
// bf16 GEMM-BT, 256x256 tile, BK=64, 512 threads = 8 waves (2Mx4N), each wave
// owns a 128x64 sub-tile = 8x4 frags of 16x16x32 MFMA. LDS double-buffered
// [2][cb][row][8] (cb = k-chunk of 8 bf16): chunk ci = it*512+tid lands at
// LDS offset ci*16B -> lane-contiguous for global_load_lds. 2-phase pipeline:
// issue stage(t+1) into buf^1, compute buf, drain vmcnt(0)+barrier, flip.
// Race-free: writes to buf^1 while reading buf; the barrier (which drains
// vmcnt+lgkmcnt) orders the flip.
// FUSED fallback (ws too small): stage A converting f32->bf16, B via nibble
// dequant, both with explicit ds_writes (same LDS layout).
// ---------------------------------------------------------------------------
template <bool FUSED>
__global__ __launch_bounds__(512, 2) void gemm_kernel(
        const bf16*  __restrict__ Ab,    // [M,K] bf16 (pre-converted, !FUSED)
        const float* __restrict__ Af,    // [M,K] f32  (FUSED)
        const bf16*  __restrict__ Wb,    // [N,K] bf16 (pre-dequant, !FUSED)
        const int*   __restrict__ Wq,    // [N,K/2] packed words (FUSED)
        const float* __restrict__ norm,  // [N] f32 (FUSED)
        const float* __restrict__ bias,  // [N] f32
        float*       __restrict__ C)     // [M,N] f32
{
    __shared__ bf16 As[2][(BK / 8) * BM * 8];   // 2 x 32 KiB
    __shared__ bf16 Bs[2][(BK / 8) * BN * 8];   // 2 x 32 KiB  -> 128 KiB total

    const int tid = threadIdx.x;

    // XCD-banded bijective swizzle: grid = 64 bm x 48 bn tiles, 3072 blocks.
    // HW round-robins linear id % 8 across XCDs -> XCD x owns bm rows
    // [x*8, x*8+8), row-major within the band: resident blocks of one XCD
    // share a single 2 MiB A panel (L2-resident).
    const int lin = blockIdx.x;
    const int xcd = lin & 7;
    const int s   = lin >> 3;              // 0..383
    const int bn  = s % 48;
    const int bm  = xcd * 8 + s / 48;
    const int m0  = bm * BM;
    const int n0  = bn * BN;

    const int lane = tid & 63;
    const int wave = tid >> 6;
    const int wm = wave >> 2, wn = wave & 3;    // 2 x 4 waves
    const int lm = lane & 15, q = lane >> 4;    // MFMA lane coords

    f32x4 acc[8][4];
#pragma unroll
    for (int i = 0; i < 8; ++i)
#pragma unroll
        for (int j = 0; j < 4; ++j) acc[i][j] = (f32x4){0.f, 0.f, 0.f, 0.f};

    // stage one BK-slice of A and B into buffer b (issue-only for !FUSED)
    auto stage = [&](int b, int k0) {
#pragma unroll
        for (int it = 0; it < 4; ++it) {
            int ci = it * 512 + tid;            // 0..2047
            int cb = ci >> 8, row = ci & 255;
            if (!FUSED) {
                async_copy16(Ab + (size_t)(m0 + row) * K_TOT + k0 + cb * 8,
                             &As[b][ci * 8]);
            } else {
                const float4* p = (const float4*)(Af + (size_t)(m0 + row) * K_TOT
                                                  + k0 + cb * 8);
                float4 a = p[0], c = p[1];
                bf16x8 o = { (bf16)a.x, (bf16)a.y, (bf16)a.z, (bf16)a.w,
                             (bf16)c.x, (bf16)c.y, (bf16)c.z, (bf16)c.w };
                *(bf16x8*)&As[b][ci * 8] = o;
            }
        }
#pragma unroll
        for (int it = 0; it < 4; ++it) {
            int ci = it * 512 + tid;
            int cb = ci >> 8, row = ci & 255;
            if (!FUSED) {
                async_copy16(Wb + (size_t)(n0 + row) * K_TOT + k0 + cb * 8,
                             &Bs[b][ci * 8]);
            } else {
                int4 qw = *(const int4*)(Wq + (size_t)(n0 + row) * (K_TOT / 2)
                                         + (k0 >> 1) + cb * 4);
                float n = norm[n0 + row];
                float sc = n * (2.0f / 15.0f);
                int v[4] = {qw.x, qw.y, qw.z, qw.w};
                bf16x8 o;
#pragma unroll
                for (int u = 0; u < 4; ++u) {
                    o[2*u]   = (bf16)((float)(v[u] & 15)        * sc - n);
                    o[2*u+1] = (bf16)((float)((v[u] >> 4) & 15) * sc - n);
                }
                *(bf16x8*)&Bs[b][ci * 8] = o;
            }
        }
    };

    // prologue: fill buffer 0
    stage(0, 0);
    asm volatile("s_waitcnt vmcnt(0)" ::: "memory");
    __syncthreads();

    int cur = 0;
    for (int k0 = 0; k0 < K_TOT; k0 += BK) {
        // issue next tile's stage first so its latency hides under the MFMAs
        if (k0 + BK < K_TOT) stage(cur ^ 1, k0 + BK);

        // compute current buffer: 2 k-steps of 32, 32 MFMA each
#pragma unroll
        for (int ks = 0; ks < 2; ++ks) {
            bf16x8 af[8], bfr[4];
            int cb = ks * 4 + q;
#pragma unroll
            for (int i = 0; i < 8; ++i) {
                int row = wm * 128 + i * 16 + lm;
                af[i] = *(const bf16x8*)&As[cur][(cb * BM + row) * 8];
            }
#pragma unroll
            for (int j = 0; j < 4; ++j) {
                int row = wn * 64 + j * 16 + lm;
                bfr[j] = *(const bf16x8*)&Bs[cur][(cb * BN + row) * 8];
            }
#pragma unroll
            for (int i = 0; i < 8; ++i)
#pragma unroll
                for (int j = 0; j < 4; ++j)
                    acc[i][j] = __builtin_amdgcn_mfma_f32_16x16x32_bf16(
                        af[i], bfr[j], acc[i][j], 0, 0, 0);
        }

        // drain staged loads + make all reads of 'cur' visible, then flip
        asm volatile("s_waitcnt vmcnt(0)" ::: "memory");
        __syncthreads();
        cur ^= 1;
    }

    // ---- epilogue: D[m = q*4+r][n = lm] per 16x16 tile; + bias, f32 out ----
    // nontemporal: C is write-once, keep it from evicting A/W panels from L2/L3
    float bj[4];
#pragma unroll
    for (int j = 0; j < 4; ++j)
        bj[j] = bias[n0 + wn * 64 + j * 16 + lm];
#pragma unroll
    for (int i = 0; i < 8; ++i) {
#pragma unroll
        for (int r = 0; r < 4; ++r) {
            size_t row  = (size_t)(m0 + wm * 128 + i * 16 + q * 4 + r);
            size_t base = row * N_TOT + n0 + wn * 64 + lm;
#pragma unroll
            for (int j = 0; j < 4; ++j)
                __builtin_nontemporal_store(acc[i][j][r] + bj[j],
                                            &C[base + j * 16]);
        }
    }
}

extern "C" void kernel_launch(void* const* d_in, const int* in_sizes, int n_in,
                              void* d_out, int out_size, void* d_ws, size_t ws_size,
                              hipStream_t stream) {
    const float* x    = (const float*)d_in[0];
    const int*   wq   = (const int*)d_in[1];
    const float* norm = (const float*)d_in[2];
    const float* bias = (const float*)d_in[3];
    float* out = (float*)d_out;

    const size_t WBYTES = (size_t)N_TOT * K_TOT * sizeof(bf16);  //  96 MiB
    const size_t XBYTES = (size_t)M_TOT * K_TOT * sizeof(bf16);  // 128 MiB
    const int nblocks = (M_TOT / BM) * (N_TOT / BN);             // 64*48 = 3072

    if (ws_size >= WBYTES + XBYTES) {
        bf16* wdq = (bf16*)d_ws;
        bf16* xb  = (bf16*)((char*)d_ws + WBYTES);
        dequant_kernel<<<(N_TOT * (K_TOT / 2) / 4) / 256, 256, 0, stream>>>(
            wq, norm, wdq);
        convert_x_kernel<<<(M_TOT * K_TOT / 8) / 256, 256, 0, stream>>>(x, xb);
        gemm_kernel<false><<<nblocks, 512, 0, stream>>>(xb, nullptr, wdq, nullptr,
                                                        nullptr, bias, out);
    } else {
        // workspace too small: fully fused staging (f32 convert + nibble dequant)
        gemm_kernel<true><<<nblocks, 512, 0, stream>>>(nullptr, x, nullptr, wq,
                                                       norm, bias, out);
    }
}